// Round 3
// baseline (15.306 us; speedup 1.0000x reference)
//
#include <hip/hip_runtime.h>
#include <math.h>

// out[b,n,m,0:3] = min_delta ; [3] = min_dist ; [4] = min_dist2(clamped) ; [5] = min_dist_norm
// One thread handles 4 consecutive m for one (b,n). Grid: (100, 8), block 256.
__global__ void __launch_bounds__(256) geom_kernel(const float* __restrict__ coords,
                                                   const float* __restrict__ lattice,
                                                   float* __restrict__ out) {
    const int N = 320;
    unsigned pos = blockIdx.x * 256u + threadIdx.x;    // < 320*80 = 25600 exactly
    int b = blockIdx.y;
    unsigned n  = pos / 80u;
    unsigned m0 = (pos - n * 80u) * 4u;

    // --- lattice -> Gram (b is block-uniform -> scalar loads) ---
    const float* lat = lattice + b * 6;
    float l0 = fminf(fmaxf(lat[0], -5.0f), 5.0f);
    float l1 = fminf(fmaxf(lat[1], -5.0f), 5.0f);
    float l2 = fminf(fmaxf(lat[2], -5.0f), 5.0f);
    float ca = fminf(fmaxf(lat[3], -0.9999f), 0.9999f);
    float cb = fminf(fmaxf(lat[4], -0.9999f), 0.9999f);
    float cg = fminf(fmaxf(lat[5], -0.9999f), 0.9999f);

    float a  = expf(l0);
    float bl = expf(l1);
    float c  = expf(l2);

    float G00 = a * a;
    float G01 = (a * bl) * cg;
    float G02 = (a * c) * cb;
    float G11 = bl * bl;
    float G12 = (bl * c) * ca;
    float G22 = c * c;

    float twoG01 = G01 + G01;
    float twoG02 = G02 + G02;
    float twoG12 = G12 + G12;

    float cell  = fmaxf((a + bl + c) / 3.0f, 1e-6f);
    float rcell = 1.0f / cell;   // hoisted; <=1ulp diff vs per-pair divide (output value only)

    // --- coords ---
    const float* cn = coords + ((size_t)b * N + n) * 3;
    float nx = cn[0], ny = cn[1], nz = cn[2];

    const float4* cmv = (const float4*)(coords + ((size_t)b * N + m0) * 3); // 16B aligned (m0%4==0)
    float4 q0 = cmv[0], q1 = cmv[1], q2 = cmv[2];
    float mx[4] = {q0.x, q0.w, q1.z, q2.y};
    float my[4] = {q0.y, q1.x, q1.w, q2.z};
    float mz[4] = {q0.z, q1.y, q2.x, q2.w};

    float res[24];

    #pragma unroll
    for (int j = 0; j < 4; ++j) {
        float dx = nx - mx[j];
        float dy = ny - my[j];
        float dz = nz - mz[j];

        // --- argmin over 27 images (bitwise-identical arithmetic to validated R2) ---
        float best = INFINITY;
        int bestk = 0;
        #pragma unroll
        for (int kx = 0; kx < 3; ++kx) {
            float e0 = dx + (float)(kx - 1);
            float u   = (e0 * G00) * e0;
            float t01 = e0 * twoG01;
            float t02 = e0 * twoG02;
            #pragma unroll
            for (int ky = 0; ky < 3; ++ky) {
                float e1 = dy + (float)(ky - 1);
                float v = fmaf(e1, fmaf(e1, G11, t01), u);
                float w = fmaf(e1, twoG12, t02);
                #pragma unroll
                for (int kz = 0; kz < 3; ++kz) {
                    float e2 = dz + (float)(kz - 1);
                    float f = fmaf(e2, G22, w);
                    float dist2 = fmaf(e2, f, v);
                    int k = kx * 9 + ky * 3 + kz;
                    if (dist2 < best) { best = dist2; bestk = k; }
                }
            }
        }

        unsigned uk = (unsigned)bestk;
        float ox = (float)(uk / 9u) - 1.0f;
        float oy = (float)((uk / 3u) % 3u) - 1.0f;
        float oz = (float)(uk % 3u) - 1.0f;

        float md2 = fmaxf(best, 0.0f);
        float mdist = (md2 > 0.0f) ? sqrtf(md2) : 0.0f;

        res[j * 6 + 0] = dx + ox;
        res[j * 6 + 1] = dy + oy;
        res[j * 6 + 2] = dz + oz;
        res[j * 6 + 3] = mdist;
        res[j * 6 + 4] = md2;
        res[j * 6 + 5] = mdist * rcell;
    }

    // 96B contiguous, 16B-aligned (m0%4==0 -> base*4 % 16 == 0)
    float4* ov = (float4*)(out + (((size_t)b * N + n) * N + m0) * 6);
    #pragma unroll
    for (int t = 0; t < 6; ++t) {
        ov[t] = make_float4(res[4 * t], res[4 * t + 1], res[4 * t + 2], res[4 * t + 3]);
    }
}

extern "C" void kernel_launch(void* const* d_in, const int* in_sizes, int n_in,
                              void* d_out, int out_size, void* d_ws, size_t ws_size,
                              hipStream_t stream) {
    const float* coords = (const float*)d_in[0];   // (8, 320, 3) f32
    const float* lattice = (const float*)d_in[1];  // (8, 6) f32
    float* out = (float*)d_out;                    // (8, 320, 320, 6) f32

    dim3 grid(100, 8);   // 100*256 = 25600 = 320 n * 80 m-quads ; y = batch
    geom_kernel<<<grid, 256, 0, stream>>>(coords, lattice, out);
}

// Round 4
// 12.619 us; speedup vs baseline: 1.2129x; 1.2129x over previous
//
#include <hip/hip_runtime.h>
#include <math.h>

// out[b,n,m,0:3] = min_delta ; [3] = min_dist ; [4] = min_dist2(clamped) ; [5] = min_dist_norm
// 1 thread = 1 (n,m) pair. Grid (400, 8) x 256: blockIdx.y = b (lattice uniform per block).
__global__ void __launch_bounds__(256) geom_kernel(const float* __restrict__ coords,
                                                   const float* __restrict__ lattice,
                                                   float* __restrict__ out) {
    const int N = 320;
    __shared__ float sc[8];
    int b = blockIdx.y;

    if (threadIdx.x == 0) {
        // lattice -> Gram, bitwise-identical to validated R2 arithmetic
        const float* lat = lattice + b * 6;
        float l0 = fminf(fmaxf(lat[0], -5.0f), 5.0f);
        float l1 = fminf(fmaxf(lat[1], -5.0f), 5.0f);
        float l2 = fminf(fmaxf(lat[2], -5.0f), 5.0f);
        float ca = fminf(fmaxf(lat[3], -0.9999f), 0.9999f);
        float cb = fminf(fmaxf(lat[4], -0.9999f), 0.9999f);
        float cg = fminf(fmaxf(lat[5], -0.9999f), 0.9999f);
        float a  = expf(l0);
        float bl = expf(l1);
        float c  = expf(l2);
        float G00 = a * a;
        float G01 = (a * bl) * cg;
        float G02 = (a * c) * cb;
        float G11 = bl * bl;
        float G12 = (bl * c) * ca;
        float G22 = c * c;
        sc[0] = G00;
        sc[1] = G11;
        sc[2] = G22;
        sc[3] = G01 + G01;
        sc[4] = G02 + G02;
        sc[5] = G12 + G12;
        sc[6] = 1.0f / fmaxf((a + bl + c) / 3.0f, 1e-6f);  // rcell (validated in R3)
    }
    __syncthreads();

    float G00 = sc[0], G11 = sc[1], G22 = sc[2];
    float twoG01 = sc[3], twoG02 = sc[4], twoG12 = sc[5];
    float rcell = sc[6];

    unsigned pos = blockIdx.x * 256u + threadIdx.x;   // < 102400 = 320*320 exactly
    unsigned n = pos / 320u;
    unsigned m = pos - n * 320u;

    const float* cn = coords + ((size_t)b * N + n) * 3;
    const float* cm = coords + ((size_t)b * N + m) * 3;
    float dx = cn[0] - cm[0];
    float dy = cn[1] - cm[1];
    float dz = cn[2] - cm[2];

    // hoisted image coordinates (bitwise-identical to in-loop dx + (k-1))
    float e0[3] = {dx + -1.0f, dx + 0.0f, dx + 1.0f};
    float e1[3] = {dy + -1.0f, dy + 0.0f, dy + 1.0f};
    float e2[3] = {dz + -1.0f, dz + 0.0f, dz + 1.0f};

    // argmin over 27 images; group = (kx,ky), min3 within group, strict < across
    // groups (k-order) => first-occurrence semantics preserved exactly.
    float best = INFINITY;
    int bestg = 0;   // packed gx*4+gy
    #pragma unroll
    for (int gx = 0; gx < 3; ++gx) {
        float E0  = e0[gx];
        float u   = (E0 * G00) * E0;
        float t01 = E0 * twoG01;
        float t02 = E0 * twoG02;
        #pragma unroll
        for (int gy = 0; gy < 3; ++gy) {
            float E1 = e1[gy];
            float v = fmaf(E1, fmaf(E1, G11, t01), u);
            float w = fmaf(E1, twoG12, t02);
            float d0 = fmaf(e2[0], fmaf(e2[0], G22, w), v);
            float d1 = fmaf(e2[1], fmaf(e2[1], G22, w), v);
            float d2 = fmaf(e2[2], fmaf(e2[2], G22, w), v);
            float gmin = fminf(fminf(d0, d1), d2);   // v_min3_f32
            if (gmin < best) { best = gmin; bestg = gx * 4 + gy; }
        }
    }

    // reconstruct winning group deterministically (bitwise replay of same fmas)
    int gx = bestg >> 2;
    int gy = bestg & 3;
    float E0 = (gx == 0) ? e0[0] : ((gx == 1) ? e0[1] : e0[2]);
    float E1 = (gy == 0) ? e1[0] : ((gy == 1) ? e1[1] : e1[2]);
    {
        float u   = (E0 * G00) * E0;
        float t01 = E0 * twoG01;
        float t02 = E0 * twoG02;
        float v = fmaf(E1, fmaf(E1, G11, t01), u);
        float w = fmaf(E1, twoG12, t02);
        float d0 = fmaf(e2[0], fmaf(e2[0], G22, w), v);
        float d1 = fmaf(e2[1], fmaf(e2[1], G22, w), v);
        float E2 = (d0 == best) ? e2[0] : ((d1 == best) ? e2[1] : e2[2]);

        float md2 = fmaxf(best, 0.0f);
        float mdist = (md2 > 0.0f) ? sqrtf(md2) : 0.0f;
        float mnorm = mdist * rcell;

        size_t base = (((size_t)b * N + n) * N + m) * 6;  // *4 bytes = 24B units, 8-aligned
        float2* ov = (float2*)(out + base);
        ov[0] = make_float2(E0, E1);
        ov[1] = make_float2(E2, mdist);
        ov[2] = make_float2(md2, mnorm);
    }
}

extern "C" void kernel_launch(void* const* d_in, const int* in_sizes, int n_in,
                              void* d_out, int out_size, void* d_ws, size_t ws_size,
                              hipStream_t stream) {
    const float* coords = (const float*)d_in[0];   // (8, 320, 3) f32
    const float* lattice = (const float*)d_in[1];  // (8, 6) f32
    float* out = (float*)d_out;                    // (8, 320, 320, 6) f32

    dim3 grid(400, 8);   // 400*256 = 102400 = 320*320 pairs per batch ; y = batch
    geom_kernel<<<grid, 256, 0, stream>>>(coords, lattice, out);
}